// Round 1
// baseline (263.044 us; speedup 1.0000x reference)
//
#include <hip/hip_runtime.h>

// ScanCausalSelfAttention: X[2,2048,1024] fp32, Wqkv[1024,3072], Wproj[1024,1024]
// out fp32 [2,2048,1024]. Internal compute bf16 MFMA + fp32 accumulate.
//
// Workspace layout (u16 bf16 elements), total 50,331,648 bytes:
//   Xb     [4096][1024]
//   Wqkvt  [3072][1024]   (transposed: row n, col k)
//   Wprojt [1024][1024]   (transposed)
//   Qb/Kb/Vb [2][16][2048][64]  (q pre-scaled by 1/8)
//   AO     [4096][1024]   (attention output, row b*T+t, col h*64+d)

using u16 = unsigned short;
using u32 = unsigned int;

typedef __bf16 bf16x8 __attribute__((ext_vector_type(8)));
typedef float f32x4 __attribute__((ext_vector_type(4)));

#define DEV __device__ __forceinline__

DEV u16 f2bf(float f) {
  union { float f; u32 u; } x; x.f = f;
  return (u16)((x.u + 0x7fffu + ((x.u >> 16) & 1u)) >> 16);  // RNE
}

DEV f32x4 mfma16(bf16x8 a, bf16x8 b, f32x4 c) {
  return __builtin_amdgcn_mfma_f32_16x16x32_bf16(a, b, c, 0, 0, 0);
}

DEV void gload_lds16(const void* g, void* l) {
  __builtin_amdgcn_global_load_lds(
      (const __attribute__((address_space(1))) void*)g,
      (__attribute__((address_space(3))) void*)l, 16, 0, 0);
}

DEV bf16x8 ld16(const u16* p) { return *(const bf16x8*)p; }

// ---------------- prep kernels ----------------

__global__ __launch_bounds__(256) void cvt_x_kernel(const float* __restrict__ X,
                                                    u16* __restrict__ Xb) {
  int i = (blockIdx.x * 256 + threadIdx.x) * 8;
  float4 a = *(const float4*)&X[i];
  float4 b = *(const float4*)&X[i + 4];
  union { u16 u[8]; uint4 v; } o;
  o.u[0] = f2bf(a.x); o.u[1] = f2bf(a.y); o.u[2] = f2bf(a.z); o.u[3] = f2bf(a.w);
  o.u[4] = f2bf(b.x); o.u[5] = f2bf(b.y); o.u[6] = f2bf(b.z); o.u[7] = f2bf(b.w);
  *(uint4*)&Xb[i] = o.v;
}

// src [R][C] fp32 -> dst [C][R] bf16
__global__ __launch_bounds__(256) void transpose_w_kernel(const float* __restrict__ W,
                                                          u16* __restrict__ Wt,
                                                          int R, int C) {
  __shared__ float tile[64][65];
  int tilesC = C >> 6;
  int tr = blockIdx.x / tilesC, tc = blockIdx.x % tilesC;
  int t = threadIdx.x;
#pragma unroll
  for (int j = 0; j < 16; ++j) {
    int idx = j * 256 + t;
    int r = idx >> 6, c = idx & 63;
    tile[r][c] = W[(tr * 64 + r) * C + tc * 64 + c];
  }
  __syncthreads();
#pragma unroll
  for (int j = 0; j < 16; ++j) {
    int idx = j * 256 + t;
    int r = idx >> 6, c = idx & 63;   // r: n-dim, c: k-dim
    Wt[(tc * 64 + r) * R + tr * 64 + c] = f2bf(tile[c][r]);
  }
}

// ---------------- GEMM (A row-major [M][1024] bf16, Bt [N][1024] bf16) ----------------
// 128x128 tile, 4 waves (2x2 of 64x64), BK=64, global_load_lds staging.
// MODE 0: scatter epilogue into Q/K/V (q scaled 0.125). MODE 1: fp32 out [M][1024].

template <int NCOLS, int MODE>
__global__ __launch_bounds__(256) void gemm_bt_kernel(
    const u16* __restrict__ A, const u16* __restrict__ Bt,
    u16* __restrict__ Qb, u16* __restrict__ Kb, u16* __restrict__ Vb,
    float* __restrict__ OF) {
  constexpr int NTN = NCOLS / 128;
  const int mt = blockIdx.x / NTN, nt = blockIdx.x % NTN;
  const int m0 = mt * 128, n0 = nt * 128;
  const int tid = threadIdx.x;
  const int wid = tid >> 6, lane = tid & 63;
  const int g = lane >> 4, li = lane & 15;
  const int wm = wid >> 1, wn = wid & 1;

  __shared__ __align__(16) u16 As[128 * 64];
  __shared__ __align__(16) u16 Bs[128 * 64];

  f32x4 acc[4][4] = {};

  for (int kt = 0; kt < 1024 / 64; ++kt) {
    __syncthreads();
#pragma unroll
    for (int iss = 0; iss < 4; ++iss) {
      int e = iss * 2048 + wid * 512 + lane * 8;
      int row = e >> 6, kk = e & 63;
      gload_lds16(&A[(size_t)(m0 + row) * 1024 + kt * 64 + kk], &As[iss * 2048 + wid * 512]);
      gload_lds16(&Bt[(size_t)(n0 + row) * 1024 + kt * 64 + kk], &Bs[iss * 2048 + wid * 512]);
    }
    __syncthreads();
#pragma unroll
    for (int ks = 0; ks < 2; ++ks) {
      bf16x8 af[4], bfr[4];
#pragma unroll
      for (int mi = 0; mi < 4; ++mi)
        af[mi] = ld16(&As[(wm * 64 + mi * 16 + li) * 64 + ks * 32 + g * 8]);
#pragma unroll
      for (int ni = 0; ni < 4; ++ni)
        bfr[ni] = ld16(&Bs[(wn * 64 + ni * 16 + li) * 64 + ks * 32 + g * 8]);
#pragma unroll
      for (int mi = 0; mi < 4; ++mi)
#pragma unroll
        for (int ni = 0; ni < 4; ++ni)
          acc[mi][ni] = mfma16(af[mi], bfr[ni], acc[mi][ni]);
    }
  }

#pragma unroll
  for (int mi = 0; mi < 4; ++mi)
#pragma unroll
    for (int ni = 0; ni < 4; ++ni)
#pragma unroll
      for (int r = 0; r < 4; ++r) {
        int rr = m0 + wm * 64 + mi * 16 + g * 4 + r;
        int cc = n0 + wn * 64 + ni * 16 + li;
        float v = acc[mi][ni][r];
        if (MODE == 0) {
          int which = cc >> 10, rem = cc & 1023;
          int h = rem >> 6, dd = rem & 63;
          int bb = rr >> 11, tt = rr & 2047;
          size_t di = ((size_t)(bb * 16 + h) * 2048 + tt) * 64 + dd;
          u16 o = f2bf(which == 0 ? v * 0.125f : v);
          if (which == 0) Qb[di];
          (which == 0 ? Qb : which == 1 ? Kb : Vb)[di] = o;
        } else {
          OF[(size_t)rr * 1024 + cc] = v;
        }
      }
}

// ---------------- causal flash attention ----------------
// grid = 32 (b*h) * 32 (q-tiles of 64). block = 4 waves, wave w owns rows w*16..w*16+15.

__global__ __launch_bounds__(256) void attn_kernel(const u16* __restrict__ Q,
                                                   const u16* __restrict__ K,
                                                   const u16* __restrict__ V,
                                                   u16* __restrict__ AO) {
  const int bid = blockIdx.x;
  const int bh = bid >> 5, qt = bid & 31;
  const int b = bh >> 4, h = bh & 15;
  const int tid = threadIdx.x;
  const int wid = tid >> 6, lane = tid & 63;
  const int g = lane >> 4, li = lane & 15;
  const int q0 = qt * 64;

  __shared__ __align__(16) u16 Ks[64 * 64];
  __shared__ __align__(16) u16 Vt[64 * 64];  // [d][key]
  __shared__ __align__(16) u16 Pb[4][16 * 64];

  const u16* Qh = Q + (size_t)bh * 2048 * 64;
  const u16* Kh = K + (size_t)bh * 2048 * 64;
  const u16* Vh = V + (size_t)bh * 2048 * 64;

  // Q fragments (rows q0 + wid*16 + li), q already scaled by 1/8
  bf16x8 qf[2];
  {
    int qrow = q0 + wid * 16 + li;
#pragma unroll
    for (int ks = 0; ks < 2; ++ks)
      qf[ks] = ld16(&Qh[(size_t)qrow * 64 + ks * 32 + g * 8]);
  }

  f32x4 accO[4] = {};
  float mrun[4], lrun[4];
#pragma unroll
  for (int r = 0; r < 4; ++r) { mrun[r] = -1e30f; lrun[r] = 0.f; }

  for (int kt = 0; kt <= qt; ++kt) {
    __syncthreads();
    // stage K linearly: Ks[key][d]
#pragma unroll
    for (int iss = 0; iss < 2; ++iss) {
      int e = iss * 2048 + wid * 512 + lane * 8;
      int row = e >> 6, dd = e & 63;
      gload_lds16(&Kh[(size_t)(kt * 64 + row) * 64 + dd], &Ks[iss * 2048 + wid * 512]);
    }
    // stage V transposed: Vt[d][key]
    {
      int key = tid >> 2, dg = (tid & 3) * 16;
      const u16* vp = &Vh[(size_t)(kt * 64 + key) * 64 + dg];
      union { u16 u[16]; uint4 v[2]; } tmp;
      tmp.v[0] = *(const uint4*)vp;
      tmp.v[1] = *(const uint4*)(vp + 8);
#pragma unroll
      for (int j = 0; j < 16; ++j) Vt[(dg + j) * 64 + key] = tmp.u[j];
    }
    __syncthreads();

    // S = Q K^T  (16 q-rows x 64 keys per wave)
    f32x4 s[4];
#pragma unroll
    for (int ni = 0; ni < 4; ++ni) s[ni] = f32x4{0.f, 0.f, 0.f, 0.f};
#pragma unroll
    for (int ks = 0; ks < 2; ++ks) {
      bf16x8 kf[4];
#pragma unroll
      for (int ni = 0; ni < 4; ++ni)
        kf[ni] = ld16(&Ks[(ni * 16 + li) * 64 + ks * 32 + g * 8]);
#pragma unroll
      for (int ni = 0; ni < 4; ++ni) s[ni] = mfma16(qf[ks], kf[ni], s[ni]);
    }

    if (kt == qt) {  // diagonal tile: causal mask
#pragma unroll
      for (int ni = 0; ni < 4; ++ni)
#pragma unroll
        for (int r = 0; r < 4; ++r) {
          int qg = q0 + wid * 16 + g * 4 + r;
          int kg = kt * 64 + ni * 16 + li;
          if (kg > qg) s[ni][r] = -1e30f;
        }
    }

    // online softmax, rows distributed as (g, reg); cols across 16 lanes x 4 frags
    float alpha[4];
#pragma unroll
    for (int r = 0; r < 4; ++r) {
      float mx = fmaxf(fmaxf(s[0][r], s[1][r]), fmaxf(s[2][r], s[3][r]));
#pragma unroll
      for (int msk = 1; msk < 16; msk <<= 1) mx = fmaxf(mx, __shfl_xor(mx, msk));
      float mnew = fmaxf(mrun[r], mx);
      alpha[r] = __expf(mrun[r] - mnew);
      mrun[r] = mnew;
      float rs = 0.f;
#pragma unroll
      for (int ni = 0; ni < 4; ++ni) {
        float p = __expf(s[ni][r] - mnew);
        s[ni][r] = p;
        rs += p;
      }
#pragma unroll
      for (int msk = 1; msk < 16; msk <<= 1) rs += __shfl_xor(rs, msk);
      lrun[r] = lrun[r] * alpha[r] + rs;
    }

    // P -> per-wave LDS (bf16), rescale accO
    u16* P = Pb[wid];
#pragma unroll
    for (int ni = 0; ni < 4; ++ni)
#pragma unroll
      for (int r = 0; r < 4; ++r) P[(g * 4 + r) * 64 + ni * 16 + li] = f2bf(s[ni][r]);
#pragma unroll
    for (int ni = 0; ni < 4; ++ni)
#pragma unroll
      for (int r = 0; r < 4; ++r) accO[ni][r] *= alpha[r];

    // O += P V
#pragma unroll
    for (int ks = 0; ks < 2; ++ks) {
      bf16x8 pf = ld16(&P[li * 64 + ks * 32 + g * 8]);
      bf16x8 vf[4];
#pragma unroll
      for (int ni = 0; ni < 4; ++ni)
        vf[ni] = ld16(&Vt[(ni * 16 + li) * 64 + ks * 32 + g * 8]);
#pragma unroll
      for (int ni = 0; ni < 4; ++ni) accO[ni] = mfma16(pf, vf[ni], accO[ni]);
    }
  }

  // normalize + write AO[b*T+t][h*64+d]
#pragma unroll
  for (int ni = 0; ni < 4; ++ni)
#pragma unroll
    for (int r = 0; r < 4; ++r) {
      int tt = q0 + wid * 16 + g * 4 + r;
      int cc = h * 64 + ni * 16 + li;
      AO[(size_t)(b * 2048 + tt) * 1024 + cc] = f2bf(accO[ni][r] / lrun[r]);
    }
}

// ---------------- launch ----------------

extern "C" void kernel_launch(void* const* d_in, const int* in_sizes, int n_in,
                              void* d_out, int out_size, void* d_ws, size_t ws_size,
                              hipStream_t stream) {
  const float* X = (const float*)d_in[0];
  const float* Wqkv = (const float*)d_in[1];
  const float* Wproj = (const float*)d_in[2];
  float* out = (float*)d_out;

  u16* ws = (u16*)d_ws;
  u16* Xb = ws;                        // 4194304
  u16* Wqkvt = Xb + 4194304;           // 3145728
  u16* Wprojt = Wqkvt + 3145728;       // 1048576
  u16* Qb = Wprojt + 1048576;          // 4194304
  u16* Kb = Qb + 4194304;              // 4194304
  u16* Vb = Kb + 4194304;              // 4194304
  u16* AO = Vb + 4194304;              // 4194304  (total 50,331,648 B)

  cvt_x_kernel<<<2048, 256, 0, stream>>>(X, Xb);
  transpose_w_kernel<<<16 * 48, 256, 0, stream>>>(Wqkv, Wqkvt, 1024, 3072);
  transpose_w_kernel<<<16 * 16, 256, 0, stream>>>(Wproj, Wprojt, 1024, 1024);
  gemm_bt_kernel<3072, 0><<<32 * 24, 256, 0, stream>>>(Xb, Wqkvt, Qb, Kb, Vb, nullptr);
  attn_kernel<<<32 * 32, 256, 0, stream>>>(Qb, Kb, Vb, AO);
  gemm_bt_kernel<1024, 1><<<32 * 8, 256, 0, stream>>>(AO, Wprojt, nullptr, nullptr, nullptr, out);
}

// Round 2
// 164.964 us; speedup vs baseline: 1.5946x; 1.5946x over previous
//
#include <hip/hip_runtime.h>

// ScanCausalSelfAttention: X[2,2048,1024] fp32, Wqkv[1024,3072], Wproj[1024,1024]
// out fp32 [2,2048,1024]. Internal compute bf16 MFMA + fp32 accumulate.
//
// Workspace layout (u16 bf16 elements), total 50,331,648 bytes:
//   Xb     [4096][1024]   (reused as VtG [32][64][2048] after gemm1)
//   Wqkvt  [3072][1024]   (transposed: row n, col k)
//   Wprojt [1024][1024]   (transposed)
//   Qb/Kb/Vb [2][16][2048][64]  (q pre-scaled by log2e/8)
//   AO     [4096][1024]   (attention output, row b*T+t, col h*64+d)

using u16 = unsigned short;
using u32 = unsigned int;

typedef __bf16 bf16x8 __attribute__((ext_vector_type(8)));
typedef float f32x4 __attribute__((ext_vector_type(4)));

#define DEV __device__ __forceinline__

DEV u16 f2bf(float f) {
  union { float f; u32 u; } x; x.f = f;
  return (u16)((x.u + 0x7fffu + ((x.u >> 16) & 1u)) >> 16);  // RNE
}

DEV f32x4 mfma16(bf16x8 a, bf16x8 b, f32x4 c) {
  return __builtin_amdgcn_mfma_f32_16x16x32_bf16(a, b, c, 0, 0, 0);
}

DEV void gload_lds16(const void* g, void* l) {
  __builtin_amdgcn_global_load_lds(
      (const __attribute__((address_space(1))) void*)g,
      (__attribute__((address_space(3))) void*)l, 16, 0, 0);
}

DEV bf16x8 ld16(const u16* p) { return *(const bf16x8*)p; }

// ---------------- prep kernels ----------------

__global__ __launch_bounds__(256) void cvt_x_kernel(const float* __restrict__ X,
                                                    u16* __restrict__ Xb) {
  int i = (blockIdx.x * 256 + threadIdx.x) * 8;
  float4 a = *(const float4*)&X[i];
  float4 b = *(const float4*)&X[i + 4];
  union { u16 u[8]; uint4 v; } o;
  o.u[0] = f2bf(a.x); o.u[1] = f2bf(a.y); o.u[2] = f2bf(a.z); o.u[3] = f2bf(a.w);
  o.u[4] = f2bf(b.x); o.u[5] = f2bf(b.y); o.u[6] = f2bf(b.z); o.u[7] = f2bf(b.w);
  *(uint4*)&Xb[i] = o.v;
}

// src [R][C] fp32 -> dst [C][R] bf16
__global__ __launch_bounds__(256) void transpose_w_kernel(const float* __restrict__ W,
                                                          u16* __restrict__ Wt,
                                                          int R, int C) {
  __shared__ float tile[64][65];
  int tilesC = C >> 6;
  int tr = blockIdx.x / tilesC, tc = blockIdx.x % tilesC;
  int t = threadIdx.x;
#pragma unroll
  for (int j = 0; j < 16; ++j) {
    int idx = j * 256 + t;
    int r = idx >> 6, c = idx & 63;
    tile[r][c] = W[(tr * 64 + r) * C + tc * 64 + c];
  }
  __syncthreads();
#pragma unroll
  for (int j = 0; j < 16; ++j) {
    int idx = j * 256 + t;
    int r = idx >> 6, c = idx & 63;   // r: n-dim, c: k-dim
    Wt[(tc * 64 + r) * R + tr * 64 + c] = f2bf(tile[c][r]);
  }
}

// V [32][2048][64] bf16 -> Vt [32][64][2048] bf16
__global__ __launch_bounds__(256) void transpose_v_kernel(const u16* __restrict__ V,
                                                          u16* __restrict__ Vt) {
  __shared__ u16 tile[64 * 65];
  int head = blockIdx.x >> 5, tt = blockIdx.x & 31;
  const u16* src = V + ((size_t)head * 2048 + tt * 64) * 64;
  u16* dst = Vt + (size_t)head * 64 * 2048 + tt * 64;
  int t = threadIdx.x;
#pragma unroll
  for (int it = 0; it < 2; ++it) {
    int idx = it * 2048 + t * 8;
    int r = idx >> 6, c = idx & 63;
    union { uint4 v; u16 u[8]; } tmp;
    tmp.v = *(const uint4*)&src[idx];
#pragma unroll
    for (int j = 0; j < 8; ++j) tile[r * 65 + c + j] = tmp.u[j];
  }
  __syncthreads();
#pragma unroll
  for (int it = 0; it < 2; ++it) {
    int idx = it * 2048 + t * 8;
    int d = idx >> 6, t0 = idx & 63;
    union { uint4 v; u16 u[8]; } tmp;
#pragma unroll
    for (int j = 0; j < 8; ++j) tmp.u[j] = tile[(t0 + j) * 65 + d];
    *(uint4*)&dst[(size_t)d * 2048 + t0] = tmp.v;
  }
}

// ---------------- GEMM (A row-major [M][1024] bf16, Bt [N][1024] bf16) ----------------
// 128x128 tile, 4 waves (2x2 of 64x64), BK=64, global_load_lds staging.
// MODE 0: scatter epilogue into Q/K/V (q scaled log2e/8). MODE 1: fp32 out [M][1024].

template <int NCOLS, int MODE>
__global__ __launch_bounds__(256) void gemm_bt_kernel(
    const u16* __restrict__ A, const u16* __restrict__ Bt,
    u16* __restrict__ Qb, u16* __restrict__ Kb, u16* __restrict__ Vb,
    float* __restrict__ OF) {
  constexpr int NTN = NCOLS / 128;
  const int mt = blockIdx.x / NTN, nt = blockIdx.x % NTN;
  const int m0 = mt * 128, n0 = nt * 128;
  const int tid = threadIdx.x;
  const int wid = tid >> 6, lane = tid & 63;
  const int g = lane >> 4, li = lane & 15;
  const int wm = wid >> 1, wn = wid & 1;

  __shared__ __align__(16) u16 As[128 * 64];
  __shared__ __align__(16) u16 Bs[128 * 64];

  f32x4 acc[4][4] = {};

  for (int kt = 0; kt < 1024 / 64; ++kt) {
    __syncthreads();
#pragma unroll
    for (int iss = 0; iss < 4; ++iss) {
      int e = iss * 2048 + wid * 512 + lane * 8;
      int row = e >> 6, kk = e & 63;
      gload_lds16(&A[(size_t)(m0 + row) * 1024 + kt * 64 + kk], &As[iss * 2048 + wid * 512]);
      gload_lds16(&Bt[(size_t)(n0 + row) * 1024 + kt * 64 + kk], &Bs[iss * 2048 + wid * 512]);
    }
    __syncthreads();
#pragma unroll
    for (int ks = 0; ks < 2; ++ks) {
      bf16x8 af[4], bfr[4];
#pragma unroll
      for (int mi = 0; mi < 4; ++mi)
        af[mi] = ld16(&As[(wm * 64 + mi * 16 + li) * 64 + ks * 32 + g * 8]);
#pragma unroll
      for (int ni = 0; ni < 4; ++ni)
        bfr[ni] = ld16(&Bs[(wn * 64 + ni * 16 + li) * 64 + ks * 32 + g * 8]);
#pragma unroll
      for (int mi = 0; mi < 4; ++mi)
#pragma unroll
        for (int ni = 0; ni < 4; ++ni)
          acc[mi][ni] = mfma16(af[mi], bfr[ni], acc[mi][ni]);
    }
  }

#pragma unroll
  for (int mi = 0; mi < 4; ++mi)
#pragma unroll
    for (int ni = 0; ni < 4; ++ni)
#pragma unroll
      for (int r = 0; r < 4; ++r) {
        int rr = m0 + wm * 64 + mi * 16 + g * 4 + r;
        int cc = n0 + wn * 64 + ni * 16 + li;
        float v = acc[mi][ni][r];
        if (MODE == 0) {
          int which = cc >> 10, rem = cc & 1023;
          int h = rem >> 6, dd = rem & 63;
          int bb = rr >> 11, tt = rr & 2047;
          size_t di = ((size_t)(bb * 16 + h) * 2048 + tt) * 64 + dd;
          // fold softmax scale (1/8) and log2(e) into Q so attn uses exp2
          u16 o = f2bf(which == 0 ? v * 0.18033688f : v);
          (which == 0 ? Qb : which == 1 ? Kb : Vb)[di] = o;
        } else {
          OF[(size_t)rr * 1024 + cc] = v;
        }
      }
}

// ---------------- causal flash attention ----------------
// grid = 1024: LPT order (longest q-tiles first). block = 4 waves, wave w owns
// q-rows w*16..w*16+15. K and V^T staged via global_load_lds with XOR-swizzled
// global source (linear LDS dest); all ds_read_b128 use the matching swizzle.

__global__ __launch_bounds__(256) void attn_kernel(const u16* __restrict__ Q,
                                                   const u16* __restrict__ K,
                                                   const u16* __restrict__ VtG,
                                                   u16* __restrict__ AO) {
  const int bid = blockIdx.x;
  const int qt = 31 - (bid >> 5);      // LPT: longest blocks dispatched first
  const int bh = bid & 31;
  const int b = bh >> 4, h = bh & 15;
  const int tid = threadIdx.x;
  const int wid = tid >> 6, lane = tid & 63;
  const int g = lane >> 4, li = lane & 15;
  const int q0 = qt * 64;

  __shared__ __align__(16) u16 Ks[2][64 * 64];
  __shared__ __align__(16) u16 Vs[2][64 * 64];   // V^T: [d][key], swizzled
  __shared__ __align__(16) u16 Pb[4][16 * 64];

  const u16* Qh = Q + (size_t)bh * 2048 * 64;
  const u16* Kh = K + (size_t)bh * 2048 * 64;
  const u16* Vh = VtG + (size_t)bh * 64 * 2048;  // [64 d][2048 t]

  // Q fragments (rows q0 + wid*16 + li), q pre-scaled by log2e/8
  bf16x8 qf[2];
  {
    int qrow = q0 + wid * 16 + li;
#pragma unroll
    for (int ks = 0; ks < 2; ++ks)
      qf[ks] = ld16(&Qh[(size_t)qrow * 64 + ks * 32 + g * 8]);
  }

  f32x4 accO[4] = {};
  float mrun[4], lrun[4];
#pragma unroll
  for (int r = 0; r < 4; ++r) { mrun[r] = -1e30f; lrun[r] = 0.f; }

  // stage tile ktile into buffer buf: LDS dest linear, global source carries
  // the inverse swizzle so reads at addr^((row&7)<<3) see logical (row,col).
  auto STAGE = [&](int buf, int ktile) {
#pragma unroll
    for (int iss = 0; iss < 2; ++iss) {
      int e = iss * 2048 + wid * 512 + lane * 8;
      int row = e >> 6;
      int c0 = (e & 63) ^ ((row & 7) << 3);
      gload_lds16(&Kh[(size_t)(ktile * 64 + row) * 64 + c0],
                  &Ks[buf][iss * 2048 + wid * 512]);
      gload_lds16(&Vh[(size_t)row * 2048 + ktile * 64 + c0],
                  &Vs[buf][iss * 2048 + wid * 512]);
    }
  };

  STAGE(0, 0);
  int cur = 0;

  for (int kt = 0; kt <= qt; ++kt) {
    __syncthreads();                       // stage(cur) landed; prev reads done
    if (kt < qt) STAGE(cur ^ 1, kt + 1);   // prefetch flies under compute

    // S = Q K^T  (16 q-rows x 64 keys per wave)
    f32x4 s[4];
#pragma unroll
    for (int ni = 0; ni < 4; ++ni) s[ni] = f32x4{0.f, 0.f, 0.f, 0.f};
#pragma unroll
    for (int ks = 0; ks < 2; ++ks) {
      bf16x8 kf[4];
#pragma unroll
      for (int ni = 0; ni < 4; ++ni)
        kf[ni] = ld16(&Ks[cur][(ni * 16 + li) * 64 + ((ks * 32 + g * 8) ^ ((li & 7) << 3))]);
#pragma unroll
      for (int ni = 0; ni < 4; ++ni) s[ni] = mfma16(qf[ks], kf[ni], s[ni]);
    }

    if (kt == qt) {  // diagonal tile: causal mask
#pragma unroll
      for (int ni = 0; ni < 4; ++ni)
#pragma unroll
        for (int r = 0; r < 4; ++r) {
          int qg = q0 + wid * 16 + g * 4 + r;
          int kg = kt * 64 + ni * 16 + li;
          if (kg > qg) s[ni][r] = -1e30f;
        }
    }

    // online softmax (log2 domain), rows (g,reg); cols across 16 lanes x 4 frags
    float alpha[4];
#pragma unroll
    for (int r = 0; r < 4; ++r) {
      float mx = fmaxf(fmaxf(s[0][r], s[1][r]), fmaxf(s[2][r], s[3][r]));
#pragma unroll
      for (int msk = 1; msk < 16; msk <<= 1) mx = fmaxf(mx, __shfl_xor(mx, msk));
      float mnew = fmaxf(mrun[r], mx);
      alpha[r] = exp2f(mrun[r] - mnew);
      mrun[r] = mnew;
      float rs = 0.f;
#pragma unroll
      for (int ni = 0; ni < 4; ++ni) {
        float p = exp2f(s[ni][r] - mnew);
        s[ni][r] = p;
        rs += p;
      }
#pragma unroll
      for (int msk = 1; msk < 16; msk <<= 1) rs += __shfl_xor(rs, msk);
      lrun[r] = lrun[r] * alpha[r] + rs;
    }

    // P -> per-wave LDS (bf16, swizzled), rescale accO
    u16* P = Pb[wid];
#pragma unroll
    for (int ni = 0; ni < 4; ++ni)
#pragma unroll
      for (int r = 0; r < 4; ++r) {
        int row = g * 4 + r;
        P[row * 64 + ((ni * 16 + li) ^ ((row & 7) << 3))] = f2bf(s[ni][r]);
      }
#pragma unroll
    for (int ni = 0; ni < 4; ++ni)
#pragma unroll
      for (int r = 0; r < 4; ++r) accO[ni][r] *= alpha[r];

    // O += P V   (wave-local P: no barrier needed)
#pragma unroll
    for (int ks = 0; ks < 2; ++ks) {
      bf16x8 pf = ld16(&P[li * 64 + ((ks * 32 + g * 8) ^ ((li & 7) << 3))]);
      bf16x8 vf[4];
#pragma unroll
      for (int ni = 0; ni < 4; ++ni)
        vf[ni] = ld16(&Vs[cur][(ni * 16 + li) * 64 + ((ks * 32 + g * 8) ^ ((li & 7) << 3))]);
#pragma unroll
      for (int ni = 0; ni < 4; ++ni) accO[ni] = mfma16(pf, vf[ni], accO[ni]);
    }
    cur ^= 1;
  }

  // normalize + write AO[b*T+t][h*64+d]
#pragma unroll
  for (int ni = 0; ni < 4; ++ni)
#pragma unroll
    for (int r = 0; r < 4; ++r) {
      int tt = q0 + wid * 16 + g * 4 + r;
      int cc = h * 64 + ni * 16 + li;
      AO[(size_t)(b * 2048 + tt) * 1024 + cc] = f2bf(accO[ni][r] / lrun[r]);
    }
}

// ---------------- launch ----------------

extern "C" void kernel_launch(void* const* d_in, const int* in_sizes, int n_in,
                              void* d_out, int out_size, void* d_ws, size_t ws_size,
                              hipStream_t stream) {
  const float* X = (const float*)d_in[0];
  const float* Wqkv = (const float*)d_in[1];
  const float* Wproj = (const float*)d_in[2];
  float* out = (float*)d_out;

  u16* ws = (u16*)d_ws;
  u16* Xb = ws;                        // 4194304 (reused as VtG after gemm1)
  u16* Wqkvt = Xb + 4194304;           // 3145728
  u16* Wprojt = Wqkvt + 3145728;       // 1048576
  u16* Qb = Wprojt + 1048576;          // 4194304
  u16* Kb = Qb + 4194304;              // 4194304
  u16* Vb = Kb + 4194304;              // 4194304
  u16* AO = Vb + 4194304;              // 4194304  (total 50,331,648 B)
  u16* VtG = Xb;                       // alias: Xb dead after gemm1

  cvt_x_kernel<<<2048, 256, 0, stream>>>(X, Xb);
  transpose_w_kernel<<<16 * 48, 256, 0, stream>>>(Wqkv, Wqkvt, 1024, 3072);
  transpose_w_kernel<<<16 * 16, 256, 0, stream>>>(Wproj, Wprojt, 1024, 1024);
  gemm_bt_kernel<3072, 0><<<32 * 24, 256, 0, stream>>>(Xb, Wqkvt, Qb, Kb, Vb, nullptr);
  transpose_v_kernel<<<1024, 256, 0, stream>>>(Vb, VtG);
  attn_kernel<<<1024, 256, 0, stream>>>(Qb, Kb, VtG, AO);
  gemm_bt_kernel<1024, 1><<<32 * 8, 256, 0, stream>>>(AO, Wprojt, nullptr, nullptr, nullptr, out);
}

// Round 3
// 138.183 us; speedup vs baseline: 1.9036x; 1.1938x over previous
//
#include <hip/hip_runtime.h>

// ScanCausalSelfAttention: X[2,2048,1024] fp32, Wqkv[1024,3072], Wproj[1024,1024]
// out fp32 [2,2048,1024]. Internal compute bf16 MFMA + fp32 accumulate.
//
// Workspace layout (u16 bf16 elements), total 50,331,648 bytes:
//   Xb     [4096][1024]   (reused as VtP [32][64][2048] after gemm1)
//   Wqkvt  [3072][1024]   (transposed: row n, col k)
//   Wprojt [1024][1024]   (transposed)
//   Qb/Kb/Vb [2][16][2048][64]  (q pre-scaled by log2e/8)
//   AO     [4096][1024]   (attention output, row b*T+t, col h*64+d)

using u16 = unsigned short;
using u32 = unsigned int;

typedef __bf16 bf16x8 __attribute__((ext_vector_type(8)));
typedef __bf16 bf16x2 __attribute__((ext_vector_type(2)));
typedef float f32x4 __attribute__((ext_vector_type(4)));

#define DEV __device__ __forceinline__

DEV u16 f2bf(float f) { __bf16 h = (__bf16)f; return *(u16*)&h; }

DEV u32 pk2(float lo, float hi) {   // 2xbf16 packed; compiler emits v_cvt_pk_bf16_f32
  bf16x2 t = {(__bf16)lo, (__bf16)hi};
  return *(u32*)&t;
}

DEV f32x4 mfma16(bf16x8 a, bf16x8 b, f32x4 c) {
  return __builtin_amdgcn_mfma_f32_16x16x32_bf16(a, b, c, 0, 0, 0);
}

DEV void gload_lds16(const void* g, void* l) {
  __builtin_amdgcn_global_load_lds(
      (const __attribute__((address_space(1))) void*)g,
      (__attribute__((address_space(3))) void*)l, 16, 0, 0);
}

DEV bf16x8 ld16(const u16* p) { return *(const bf16x8*)p; }

// key permutation inside each 64-key block of V^T storage: slot -> key such
// that PV's B-fragment (lane's own 16 post-softmax P values, packed in
// register order) contracts against the right V rows. Bijective.
DEV int vperm(int slot) {
  return ((((slot >> 4) & 2) | ((slot >> 2) & 1)) << 4) + (((slot >> 3) & 3) << 2) + (slot & 3);
}

// ---------------- prep kernels ----------------

__global__ __launch_bounds__(256) void cvt_x_kernel(const float* __restrict__ X,
                                                    u16* __restrict__ Xb) {
  int i = (blockIdx.x * 256 + threadIdx.x) * 8;
  float4 a = *(const float4*)&X[i];
  float4 b = *(const float4*)&X[i + 4];
  union { u16 u[8]; uint4 v; } o;
  o.u[0] = f2bf(a.x); o.u[1] = f2bf(a.y); o.u[2] = f2bf(a.z); o.u[3] = f2bf(a.w);
  o.u[4] = f2bf(b.x); o.u[5] = f2bf(b.y); o.u[6] = f2bf(b.z); o.u[7] = f2bf(b.w);
  *(uint4*)&Xb[i] = o.v;
}

// src [R][C] fp32 -> dst [C][R] bf16
__global__ __launch_bounds__(256) void transpose_w_kernel(const float* __restrict__ W,
                                                          u16* __restrict__ Wt,
                                                          int R, int C) {
  __shared__ float tile[64][65];
  int tilesC = C >> 6;
  int tr = blockIdx.x / tilesC, tc = blockIdx.x % tilesC;
  int t = threadIdx.x;
#pragma unroll
  for (int j = 0; j < 16; ++j) {
    int idx = j * 256 + t;
    int r = idx >> 6, c = idx & 63;
    tile[r][c] = W[(tr * 64 + r) * C + tc * 64 + c];
  }
  __syncthreads();
#pragma unroll
  for (int j = 0; j < 16; ++j) {
    int idx = j * 256 + t;
    int r = idx >> 6, c = idx & 63;   // r: n-dim, c: k-dim
    Wt[(tc * 64 + r) * R + tr * 64 + c] = f2bf(tile[c][r]);
  }
}

// V [32][2048][64] bf16 -> VtP [32][64][2048] bf16, keys pi-permuted per 64-block
__global__ __launch_bounds__(256) void transpose_v_kernel(const u16* __restrict__ V,
                                                          u16* __restrict__ Vt) {
  __shared__ u16 tile[64 * 65];
  int head = blockIdx.x >> 5, tt = blockIdx.x & 31;
  const u16* src = V + ((size_t)head * 2048 + tt * 64) * 64;
  u16* dst = Vt + (size_t)head * 64 * 2048 + tt * 64;
  int t = threadIdx.x;
#pragma unroll
  for (int it = 0; it < 2; ++it) {
    int idx = it * 2048 + t * 8;
    int r = idx >> 6, c = idx & 63;   // r: key_local, c: d
    union { uint4 v; u16 u[8]; } tmp;
    tmp.v = *(const uint4*)&src[idx];
#pragma unroll
    for (int j = 0; j < 8; ++j) tile[r * 65 + c + j] = tmp.u[j];
  }
  __syncthreads();
#pragma unroll
  for (int it = 0; it < 2; ++it) {
    int idx = it * 2048 + t * 8;
    int d = idx >> 6, s0 = idx & 63;  // s0: slot base (8-aligned)
    union { uint4 v; u16 u[8]; } tmp;
#pragma unroll
    for (int j = 0; j < 8; ++j) tmp.u[j] = tile[vperm(s0 + j) * 65 + d];
    *(uint4*)&dst[(size_t)d * 2048 + s0] = tmp.v;
  }
}

// ---------------- GEMM (A row-major [M][1024] bf16, Bt [N][1024] bf16) ----------------
// 128x128 tile, 4 waves (2x2 of 64x64), BK=64, global_load_lds staging.
// MODE 0: scatter epilogue into Q/K/V (q scaled log2e/8). MODE 1: fp32 out [M][1024].

template <int NCOLS, int MODE>
__global__ __launch_bounds__(256) void gemm_bt_kernel(
    const u16* __restrict__ A, const u16* __restrict__ Bt,
    u16* __restrict__ Qb, u16* __restrict__ Kb, u16* __restrict__ Vb,
    float* __restrict__ OF) {
  constexpr int NTN = NCOLS / 128;
  const int mt = blockIdx.x / NTN, nt = blockIdx.x % NTN;
  const int m0 = mt * 128, n0 = nt * 128;
  const int tid = threadIdx.x;
  const int wid = tid >> 6, lane = tid & 63;
  const int g = lane >> 4, li = lane & 15;
  const int wm = wid >> 1, wn = wid & 1;

  __shared__ __align__(16) u16 As[128 * 64];
  __shared__ __align__(16) u16 Bs[128 * 64];

  f32x4 acc[4][4] = {};

  for (int kt = 0; kt < 1024 / 64; ++kt) {
    __syncthreads();
#pragma unroll
    for (int iss = 0; iss < 4; ++iss) {
      int e = iss * 2048 + wid * 512 + lane * 8;
      int row = e >> 6, kk = e & 63;
      gload_lds16(&A[(size_t)(m0 + row) * 1024 + kt * 64 + kk], &As[iss * 2048 + wid * 512]);
      gload_lds16(&Bt[(size_t)(n0 + row) * 1024 + kt * 64 + kk], &Bs[iss * 2048 + wid * 512]);
    }
    __syncthreads();
#pragma unroll
    for (int ks = 0; ks < 2; ++ks) {
      bf16x8 af[4], bfr[4];
#pragma unroll
      for (int mi = 0; mi < 4; ++mi)
        af[mi] = ld16(&As[(wm * 64 + mi * 16 + li) * 64 + ks * 32 + g * 8]);
#pragma unroll
      for (int ni = 0; ni < 4; ++ni)
        bfr[ni] = ld16(&Bs[(wn * 64 + ni * 16 + li) * 64 + ks * 32 + g * 8]);
#pragma unroll
      for (int mi = 0; mi < 4; ++mi)
#pragma unroll
        for (int ni = 0; ni < 4; ++ni)
          acc[mi][ni] = mfma16(af[mi], bfr[ni], acc[mi][ni]);
    }
  }

#pragma unroll
  for (int mi = 0; mi < 4; ++mi)
#pragma unroll
    for (int ni = 0; ni < 4; ++ni)
#pragma unroll
      for (int r = 0; r < 4; ++r) {
        int rr = m0 + wm * 64 + mi * 16 + g * 4 + r;
        int cc = n0 + wn * 64 + ni * 16 + li;
        float v = acc[mi][ni][r];
        if (MODE == 0) {
          int which = cc >> 10, rem = cc & 1023;
          int h = rem >> 6, dd = rem & 63;
          int bb = rr >> 11, tt = rr & 2047;
          size_t di = ((size_t)(bb * 16 + h) * 2048 + tt) * 64 + dd;
          // fold softmax scale (1/8) and log2(e) into Q so attn uses exp2
          u16 o = f2bf(which == 0 ? v * 0.18033688f : v);
          (which == 0 ? Qb : which == 1 ? Kb : Vb)[di] = o;
        } else {
          OF[(size_t)rr * 1024 + cc] = v;
        }
      }
}

// ---------------- causal flash attention (swapped-operand, in-register softmax) ----
// grid = 1024, LPT order. 4 waves, wave w owns q-rows w*16..w*16+15; each lane's
// q = w*16 + (lane&15); its softmax state (mrun/lrun) is lane-local scalars.
// S^T = mfma(K,Q) puts 16 S-values of the lane's q-row in registers; PV is
// computed as O^T = mfma(V^T, P) with V keys pre-permuted (vperm) in global so
// the lane's own packed P registers ARE the B-fragment. No P LDS, 4 shfl/tile.

__global__ __launch_bounds__(256) void attn_kernel(const u16* __restrict__ Q,
                                                   const u16* __restrict__ K,
                                                   const u16* __restrict__ VtP,
                                                   u16* __restrict__ AO) {
  const int bid = blockIdx.x;
  const int qt = 31 - (bid >> 5);      // LPT: longest blocks dispatched first
  const int bh = bid & 31;
  const int b = bh >> 4, h = bh & 15;
  const int tid = threadIdx.x;
  const int wid = tid >> 6, lane = tid & 63;
  const int g = lane >> 4, li = lane & 15;
  const int q0 = qt * 64;

  __shared__ __align__(16) u16 Ks[2][64 * 64];
  __shared__ __align__(16) u16 Vs[2][64 * 64];   // V^T: [d][slot], keys vperm'd

  const u16* Qh = Q + (size_t)bh * 2048 * 64;
  const u16* Kh = K + (size_t)bh * 2048 * 64;
  const u16* Vh = VtP + (size_t)bh * 64 * 2048;

  const int qrow = q0 + wid * 16 + li;   // this lane's q row
  bf16x8 qf[2];
#pragma unroll
  for (int ks = 0; ks < 2; ++ks)
    qf[ks] = ld16(&Qh[(size_t)qrow * 64 + ks * 32 + g * 8]);

  f32x4 accO[4] = {};                    // O^T: accO[mi][r] = O[qrow][mi*16+g*4+r]
  float mrun = -1e30f, lrun = 0.f;

  auto STAGE = [&](int buf, int ktile) {
#pragma unroll
    for (int iss = 0; iss < 2; ++iss) {
      int e = iss * 2048 + wid * 512 + lane * 8;
      int row = e >> 6;
      int c0 = (e & 63) ^ ((row & 7) << 3);
      gload_lds16(&Kh[(size_t)(ktile * 64 + row) * 64 + c0],
                  &Ks[buf][iss * 2048 + wid * 512]);
      gload_lds16(&Vh[(size_t)row * 2048 + ktile * 64 + c0],
                  &Vs[buf][iss * 2048 + wid * 512]);
    }
  };

  STAGE(0, 0);
  int cur = 0;

  for (int kt = 0; kt <= qt; ++kt) {
    __syncthreads();                       // stage(cur) landed; prev reads done
    if (kt < qt) STAGE(cur ^ 1, kt + 1);   // prefetch flies under compute

    // S^T = K Q^T: s[ni][r] = S[key = kt*64 + ni*16 + g*4 + r][q = qrow]
    f32x4 s[4];
#pragma unroll
    for (int ni = 0; ni < 4; ++ni) s[ni] = f32x4{0.f, 0.f, 0.f, 0.f};
#pragma unroll
    for (int ks = 0; ks < 2; ++ks) {
      bf16x8 kf[4];
#pragma unroll
      for (int ni = 0; ni < 4; ++ni)
        kf[ni] = ld16(&Ks[cur][(ni * 16 + li) * 64 + ((ks * 32 + g * 8) ^ ((li & 7) << 3))]);
#pragma unroll
      for (int ni = 0; ni < 4; ++ni) s[ni] = mfma16(kf[ni], qf[ks], s[ni]);
    }

    if (kt == qt) {  // diagonal tile: causal mask (key_local > q_local)
      int ql = wid * 16 + li;
#pragma unroll
      for (int ni = 0; ni < 4; ++ni)
#pragma unroll
        for (int r = 0; r < 4; ++r)
          if (ni * 16 + g * 4 + r > ql) s[ni][r] = -1e30f;
    }

    // in-lane row max over 16 values + 2 shfl across g-groups
    float pmax;
    {
      float m01 = fmaxf(fmaxf(fmaxf(s[0][0], s[0][1]), fmaxf(s[0][2], s[0][3])),
                        fmaxf(fmaxf(s[1][0], s[1][1]), fmaxf(s[1][2], s[1][3])));
      float m23 = fmaxf(fmaxf(fmaxf(s[2][0], s[2][1]), fmaxf(s[2][2], s[2][3])),
                        fmaxf(fmaxf(s[3][0], s[3][1]), fmaxf(s[3][2], s[3][3])));
      pmax = fmaxf(m01, m23);
      pmax = fmaxf(pmax, __shfl_xor(pmax, 16));
      pmax = fmaxf(pmax, __shfl_xor(pmax, 32));
    }

    // defer-max (T13): only rescale when the running max grew by > 8 (log2)
    if (!__all(pmax - mrun <= 8.0f)) {
      float mnew = fmaxf(mrun, pmax);
      float al = exp2f(mrun - mnew);
      mrun = mnew;
      lrun *= al;
#pragma unroll
      for (int mi = 0; mi < 4; ++mi) accO[mi] *= al;
    }

    // exp2 + in-lane sum + 2 shfl
    float rs;
    {
#pragma unroll
      for (int ni = 0; ni < 4; ++ni)
#pragma unroll
        for (int r = 0; r < 4; ++r) s[ni][r] = exp2f(s[ni][r] - mrun);
      float a0 = (s[0][0] + s[0][1]) + (s[0][2] + s[0][3]);
      float a1 = (s[1][0] + s[1][1]) + (s[1][2] + s[1][3]);
      float a2 = (s[2][0] + s[2][1]) + (s[2][2] + s[2][3]);
      float a3 = (s[3][0] + s[3][1]) + (s[3][2] + s[3][3]);
      rs = (a0 + a1) + (a2 + a3);
      rs += __shfl_xor(rs, 16);
      rs += __shfl_xor(rs, 32);
      lrun += rs;
    }

    // pack P into the two PV B-fragments (register-only, matches vperm layout)
    union { u32 u[4]; bf16x8 v; } pf0, pf1;
    pf0.u[0] = pk2(s[0][0], s[0][1]); pf0.u[1] = pk2(s[0][2], s[0][3]);
    pf0.u[2] = pk2(s[1][0], s[1][1]); pf0.u[3] = pk2(s[1][2], s[1][3]);
    pf1.u[0] = pk2(s[2][0], s[2][1]); pf1.u[1] = pk2(s[2][2], s[2][3]);
    pf1.u[2] = pk2(s[3][0], s[3][1]); pf1.u[3] = pk2(s[3][2], s[3][3]);

    // O^T += V^T P : accO[mi] over d = mi*16 + g*4 + r, q = qrow
#pragma unroll
    for (int ks = 0; ks < 2; ++ks) {
      bf16x8 pf = ks ? pf1.v : pf0.v;
#pragma unroll
      for (int mi = 0; mi < 4; ++mi) {
        bf16x8 vf = ld16(&Vs[cur][(mi * 16 + li) * 64 + ((ks * 32 + g * 8) ^ ((li & 7) << 3))]);
        accO[mi] = mfma16(vf, pf, accO[mi]);
      }
    }
    cur ^= 1;
  }

  // epilogue: normalize, transpose through LDS (reuse Ks), coalesced stores
  float inv = __builtin_amdgcn_rcpf(lrun);
  __syncthreads();
  u16* E = (u16*)Ks;                    // [64 q][64 d], XOR-swizzled
  int erow = wid * 16 + li;
#pragma unroll
  for (int mi = 0; mi < 4; ++mi) {
    uint2 wv;
    wv.x = pk2(accO[mi][0] * inv, accO[mi][1] * inv);
    wv.y = pk2(accO[mi][2] * inv, accO[mi][3] * inv);
    *(uint2*)&E[erow * 64 + ((mi * 16 + g * 4) ^ ((li & 7) << 3))] = wv;
  }
  __syncthreads();
#pragma unroll
  for (int pass = 0; pass < 2; ++pass) {
    int idx = pass * 2048 + tid * 8;
    int row = idx >> 6, col = idx & 63;
    uint4 val = *(uint4*)&E[row * 64 + (col ^ ((row & 7) << 3))];
    *(uint4*)&AO[(size_t)(b * 2048 + q0 + row) * 1024 + h * 64 + col] = val;
  }
}

// ---------------- launch ----------------

extern "C" void kernel_launch(void* const* d_in, const int* in_sizes, int n_in,
                              void* d_out, int out_size, void* d_ws, size_t ws_size,
                              hipStream_t stream) {
  const float* X = (const float*)d_in[0];
  const float* Wqkv = (const float*)d_in[1];
  const float* Wproj = (const float*)d_in[2];
  float* out = (float*)d_out;

  u16* ws = (u16*)d_ws;
  u16* Xb = ws;                        // 4194304 (reused as VtP after gemm1)
  u16* Wqkvt = Xb + 4194304;           // 3145728
  u16* Wprojt = Wqkvt + 3145728;       // 1048576
  u16* Qb = Wprojt + 1048576;          // 4194304
  u16* Kb = Qb + 4194304;              // 4194304
  u16* Vb = Kb + 4194304;              // 4194304
  u16* AO = Vb + 4194304;              // 4194304  (total 50,331,648 B)
  u16* VtP = Xb;                       // alias: Xb dead after gemm1

  cvt_x_kernel<<<2048, 256, 0, stream>>>(X, Xb);
  transpose_w_kernel<<<16 * 48, 256, 0, stream>>>(Wqkv, Wqkvt, 1024, 3072);
  transpose_w_kernel<<<16 * 16, 256, 0, stream>>>(Wproj, Wprojt, 1024, 1024);
  gemm_bt_kernel<3072, 0><<<32 * 24, 256, 0, stream>>>(Xb, Wqkvt, Qb, Kb, Vb, nullptr);
  transpose_v_kernel<<<1024, 256, 0, stream>>>(Vb, VtP);
  attn_kernel<<<1024, 256, 0, stream>>>(Qb, Kb, VtP, AO);
  gemm_bt_kernel<1024, 1><<<32 * 8, 256, 0, stream>>>(AO, Wprojt, nullptr, nullptr, nullptr, out);
}

// Round 4
// 123.184 us; speedup vs baseline: 2.1354x; 1.1218x over previous
//
#include <hip/hip_runtime.h>

// ScanCausalSelfAttention: X[2,2048,1024] fp32, Wqkv[1024,3072], Wproj[1024,1024]
// out fp32 [2,2048,1024]. Internal compute bf16 MFMA + fp32 accumulate.
//
// Workspace layout (u16 bf16 elements), total 50,331,648 bytes:
//   Xb     [4096][1024]   (reused as VtP [32][64][2048] after gemm1)
//   Wqkvt  [3072][1024]   (transposed: row n, col k)
//   Wprojt [1024][1024]   (transposed)
//   Qb/Kb/Vb [2][16][2048][64]  (q pre-scaled by log2e/8)
//   AO     [4096][1024]   (attention output, row b*T+t, col h*64+d)

using u16 = unsigned short;
using u32 = unsigned int;

typedef __bf16 bf16x8 __attribute__((ext_vector_type(8)));
typedef __bf16 bf16x2 __attribute__((ext_vector_type(2)));
typedef float f32x4 __attribute__((ext_vector_type(4)));

#define DEV __device__ __forceinline__

DEV u16 f2bf(float f) { __bf16 h = (__bf16)f; return *(u16*)&h; }

DEV u32 pk2(float lo, float hi) {   // 2xbf16 packed; compiler emits v_cvt_pk_bf16_f32
  bf16x2 t = {(__bf16)lo, (__bf16)hi};
  return *(u32*)&t;
}

DEV f32x4 mfma16(bf16x8 a, bf16x8 b, f32x4 c) {
  return __builtin_amdgcn_mfma_f32_16x16x32_bf16(a, b, c, 0, 0, 0);
}

DEV void gload_lds16(const void* g, void* l) {
  __builtin_amdgcn_global_load_lds(
      (const __attribute__((address_space(1))) void*)g,
      (__attribute__((address_space(3))) void*)l, 16, 0, 0);
}

DEV bf16x8 ld16(const u16* p) { return *(const bf16x8*)p; }

DEV void BAR() {
  __builtin_amdgcn_s_barrier();
  __builtin_amdgcn_sched_barrier(0);
}

// key permutation inside each 64-key block of V^T storage (see attn PV).
DEV int vperm(int slot) {
  return ((((slot >> 4) & 2) | ((slot >> 2) & 1)) << 4) + (((slot >> 3) & 3) << 2) + (slot & 3);
}

// ---------------- prep kernels ----------------

__global__ __launch_bounds__(256) void cvt_x_kernel(const float* __restrict__ X,
                                                    u16* __restrict__ Xb) {
  int i = (blockIdx.x * 256 + threadIdx.x) * 8;
  float4 a = *(const float4*)&X[i];
  float4 b = *(const float4*)&X[i + 4];
  union { u16 u[8]; uint4 v; } o;
  o.u[0] = f2bf(a.x); o.u[1] = f2bf(a.y); o.u[2] = f2bf(a.z); o.u[3] = f2bf(a.w);
  o.u[4] = f2bf(b.x); o.u[5] = f2bf(b.y); o.u[6] = f2bf(b.z); o.u[7] = f2bf(b.w);
  *(uint4*)&Xb[i] = o.v;
}

// src [R][C] fp32 -> dst [C][R] bf16
__global__ __launch_bounds__(256) void transpose_w_kernel(const float* __restrict__ W,
                                                          u16* __restrict__ Wt,
                                                          int R, int C) {
  __shared__ float tile[64][65];
  int tilesC = C >> 6;
  int tr = blockIdx.x / tilesC, tc = blockIdx.x % tilesC;
  int t = threadIdx.x;
#pragma unroll
  for (int j = 0; j < 16; ++j) {
    int idx = j * 256 + t;
    int r = idx >> 6, c = idx & 63;
    tile[r][c] = W[(tr * 64 + r) * C + tc * 64 + c];
  }
  __syncthreads();
#pragma unroll
  for (int j = 0; j < 16; ++j) {
    int idx = j * 256 + t;
    int r = idx >> 6, c = idx & 63;   // r: n-dim, c: k-dim
    Wt[(tc * 64 + r) * R + tr * 64 + c] = f2bf(tile[c][r]);
  }
}

// V [32][2048][64] bf16 -> VtP [32][64][2048] bf16, keys pi-permuted per 64-block
__global__ __launch_bounds__(256) void transpose_v_kernel(const u16* __restrict__ V,
                                                          u16* __restrict__ Vt) {
  __shared__ u16 tile[64 * 65];
  int head = blockIdx.x >> 5, tt = blockIdx.x & 31;
  const u16* src = V + ((size_t)head * 2048 + tt * 64) * 64;
  u16* dst = Vt + (size_t)head * 64 * 2048 + tt * 64;
  int t = threadIdx.x;
#pragma unroll
  for (int it = 0; it < 2; ++it) {
    int idx = it * 2048 + t * 8;
    int r = idx >> 6, c = idx & 63;   // r: key_local, c: d
    union { uint4 v; u16 u[8]; } tmp;
    tmp.v = *(const uint4*)&src[idx];
#pragma unroll
    for (int j = 0; j < 8; ++j) tile[r * 65 + c + j] = tmp.u[j];
  }
  __syncthreads();
#pragma unroll
  for (int it = 0; it < 2; ++it) {
    int idx = it * 2048 + t * 8;
    int d = idx >> 6, s0 = idx & 63;  // s0: slot base (8-aligned)
    union { uint4 v; u16 u[8]; } tmp;
#pragma unroll
    for (int j = 0; j < 8; ++j) tmp.u[j] = tile[vperm(s0 + j) * 65 + d];
    *(uint4*)&dst[(size_t)d * 2048 + s0] = tmp.v;
  }
}

// ---------------- GEMM1: 256x256 tile, 8-phase counted-vmcnt pipeline ----------------
// A [4096][1024] bf16, Bt [3072][1024] bf16 -> scatter epilogue into Q/K/V.
// 8 waves (2M x 4N), per-wave output 128x64. BK=64 split into ks0/ks1.
// LDS: 4 half-tile streams (A0,A1,B0,B1 = 128x64 each) x 2 parity buffers = 128 KB.
// Per K-tile group t (parity p = t&1), 4 phases:
//   ph1: ds_read B(ks0)+A(ks0) [12]; issue t+1.B1 -> buf p^1; bar; 16 MFMA ks0 ni{0,1}; bar
//   ph2: ds_read A(ks1) [8];                        bar; 16 MFMA ks0 ni{2,3}; bar
//   ph3: ds_read B(ks1) [4];                        bar; 16 MFMA ks1 ni{0,1}; bar
//   ph4: issue t+2.{A0,A1,B0} -> buf p (reads of those regions done ph2/ph3);
//        bar; 16 MFMA ks1 ni{2,3}; vmcnt(6); bar
// Boundary proof: tile t+1's newest share (B1, issued ph1 of group t) has exactly
// 3 half-tile-shares (6 loads) issued after it -> per-wave vmcnt(6) + barrier
// guarantees every wave's shares of tile t+1 landed before group t+1 reads.

__global__ __launch_bounds__(512, 2) void gemm256_qkv_kernel(
    const u16* __restrict__ A, const u16* __restrict__ Bt,
    u16* __restrict__ Qb, u16* __restrict__ Kb, u16* __restrict__ Vb) {
  int bid = blockIdx.x;
  int bid2 = (bid & 7) * 24 + (bid >> 3);   // XCD swizzle, 192 % 8 == 0
  const int mt = bid2 / 12, nt = bid2 % 12;
  const int m0 = mt * 256, n0 = nt * 256;
  const int tid = threadIdx.x;
  const int wid = tid >> 6, lane = tid & 63;
  const int g = lane >> 4, li = lane & 15;
  const int wm = wid >> 2, wn = wid & 3;    // 2 x 4 wave grid

  __shared__ __align__(16) u16 lds[65536];  // 128 KB

  // staging geometry: per gload-pair, lane covers row (lane>>3), col (lane&7)*8
  const int srow = lane >> 3;
  const int scol = ((lane & 7) * 8) ^ ((srow & 7) << 3);  // inverse swizzle at source

  // issue one half-tile (2 x global_load_lds per wave)
  // stream s: 0=A rows[0,128), 1=A rows[128,256), 2=B rows[0,128), 3=B rows[128,256)
  auto ISSUE = [&](int s, int kt) {
    const int p = kt & 1;
    const u16* base = (s < 2) ? &A[(size_t)(m0 + s * 128) * 1024]
                              : &Bt[(size_t)(n0 + (s - 2) * 128) * 1024];
#pragma unroll
    for (int is2 = 0; is2 < 2; ++is2) {
      int row = is2 * 64 + wid * 8 + srow;
      gload_lds16(&base[(size_t)row * 1024 + kt * 64 + scol],
                  &lds[s * 16384 + p * 8192 + is2 * 4096 + wid * 512]);
    }
  };

  auto LDA = [&](int p, int ks, bf16x8* aF) {
#pragma unroll
    for (int mi = 0; mi < 8; ++mi) {
      int row = mi * 16 + li;
      aF[mi] = ld16(&lds[wm * 16384 + p * 8192 + row * 64 +
                         ((ks * 32 + g * 8) ^ ((li & 7) << 3))]);
    }
  };
  auto LDB = [&](int p, int ks, bf16x8* bF) {
    int s = 2 + (wn >> 1);
#pragma unroll
    for (int ni = 0; ni < 4; ++ni) {
      int row = (wn & 1) * 64 + ni * 16 + li;
      bF[ni] = ld16(&lds[s * 16384 + p * 8192 + row * 64 +
                         ((ks * 32 + g * 8) ^ ((li & 7) << 3))]);
    }
  };

  f32x4 acc[8][4] = {};
  bf16x8 a0[8], a1[8], bF[4];

  // prologue: tile 0 complete, tile 1 A0/A1/B0 (B1 follows at group 0 ph1)
  ISSUE(0, 0); ISSUE(1, 0); ISSUE(2, 0); ISSUE(3, 0);
  ISSUE(0, 1); ISSUE(1, 1); ISSUE(2, 1);
  asm volatile("s_waitcnt vmcnt(6)" ::: "memory");
  BAR();

  for (int t = 0; t < 16; ++t) {
    const int p = t & 1;
    // ---- phase 1 ----
    LDB(p, 0, bF);
    LDA(p, 0, a0);
    if (t + 1 < 16) ISSUE(3, t + 1);
    BAR();
    __builtin_amdgcn_s_setprio(1);
#pragma unroll
    for (int mi = 0; mi < 8; ++mi) {
      acc[mi][0] = mfma16(a0[mi], bF[0], acc[mi][0]);
      acc[mi][1] = mfma16(a0[mi], bF[1], acc[mi][1]);
    }
    __builtin_amdgcn_s_setprio(0);
    BAR();
    // ---- phase 2 ----
    LDA(p, 1, a1);
    BAR();
    __builtin_amdgcn_s_setprio(1);
#pragma unroll
    for (int mi = 0; mi < 8; ++mi) {
      acc[mi][2] = mfma16(a0[mi], bF[2], acc[mi][2]);
      acc[mi][3] = mfma16(a0[mi], bF[3], acc[mi][3]);
    }
    __builtin_amdgcn_s_setprio(0);
    BAR();
    // ---- phase 3 ----
    LDB(p, 1, bF);           // overwrites bF: old values consumed in ph2
    BAR();
    __builtin_amdgcn_s_setprio(1);
#pragma unroll
    for (int mi = 0; mi < 8; ++mi) {
      acc[mi][0] = mfma16(a1[mi], bF[0], acc[mi][0]);
      acc[mi][1] = mfma16(a1[mi], bF[1], acc[mi][1]);
    }
    __builtin_amdgcn_s_setprio(0);
    BAR();
    // ---- phase 4 ----
    if (t + 2 < 16) { ISSUE(0, t + 2); ISSUE(1, t + 2); ISSUE(2, t + 2); }
    BAR();
    __builtin_amdgcn_s_setprio(1);
#pragma unroll
    for (int mi = 0; mi < 8; ++mi) {
      acc[mi][2] = mfma16(a1[mi], bF[2], acc[mi][2]);
      acc[mi][3] = mfma16(a1[mi], bF[3], acc[mi][3]);
    }
    __builtin_amdgcn_s_setprio(0);
    if (t + 2 < 16) {
      asm volatile("s_waitcnt vmcnt(6)" ::: "memory");
    } else {
      asm volatile("s_waitcnt vmcnt(0)" ::: "memory");
    }
    BAR();
  }

  // epilogue: scatter into Q/K/V (q pre-scaled by log2e/8 for exp2 softmax)
#pragma unroll
  for (int mi = 0; mi < 8; ++mi)
#pragma unroll
    for (int ni = 0; ni < 4; ++ni)
#pragma unroll
      for (int r = 0; r < 4; ++r) {
        int rr = m0 + wm * 128 + mi * 16 + g * 4 + r;
        int cc = n0 + wn * 64 + ni * 16 + li;
        float v = acc[mi][ni][r];
        int which = cc >> 10, rem = cc & 1023;
        int h = rem >> 6, dd = rem & 63;
        int bb = rr >> 11, tt = rr & 2047;
        size_t di = ((size_t)(bb * 16 + h) * 2048 + tt) * 64 + dd;
        u16 o = f2bf(which == 0 ? v * 0.18033688f : v);
        (which == 0 ? Qb : which == 1 ? Kb : Vb)[di] = o;
      }
}

// ---------------- GEMM2 (old 128x128 structure): A [M][1024] x Bt [N][1024] ----------
__global__ __launch_bounds__(256) void gemm_proj_kernel(
    const u16* __restrict__ A, const u16* __restrict__ Bt, float* __restrict__ OF) {
  constexpr int NTN = 1024 / 128;
  const int mt = blockIdx.x / NTN, nt = blockIdx.x % NTN;
  const int m0 = mt * 128, n0 = nt * 128;
  const int tid = threadIdx.x;
  const int wid = tid >> 6, lane = tid & 63;
  const int g = lane >> 4, li = lane & 15;
  const int wm = wid >> 1, wn = wid & 1;

  __shared__ __align__(16) u16 As[128 * 64];
  __shared__ __align__(16) u16 Bs[128 * 64];

  f32x4 acc[4][4] = {};

  for (int kt = 0; kt < 1024 / 64; ++kt) {
    __syncthreads();
#pragma unroll
    for (int iss = 0; iss < 4; ++iss) {
      int e = iss * 2048 + wid * 512 + lane * 8;
      int row = e >> 6, kk = e & 63;
      gload_lds16(&A[(size_t)(m0 + row) * 1024 + kt * 64 + kk], &As[iss * 2048 + wid * 512]);
      gload_lds16(&Bt[(size_t)(n0 + row) * 1024 + kt * 64 + kk], &Bs[iss * 2048 + wid * 512]);
    }
    __syncthreads();
#pragma unroll
    for (int ks = 0; ks < 2; ++ks) {
      bf16x8 af[4], bfr[4];
#pragma unroll
      for (int mi = 0; mi < 4; ++mi)
        af[mi] = ld16(&As[(wm * 64 + mi * 16 + li) * 64 + ks * 32 + g * 8]);
#pragma unroll
      for (int ni = 0; ni < 4; ++ni)
        bfr[ni] = ld16(&Bs[(wn * 64 + ni * 16 + li) * 64 + ks * 32 + g * 8]);
#pragma unroll
      for (int mi = 0; mi < 4; ++mi)
#pragma unroll
        for (int ni = 0; ni < 4; ++ni)
          acc[mi][ni] = mfma16(af[mi], bfr[ni], acc[mi][ni]);
    }
  }

#pragma unroll
  for (int mi = 0; mi < 4; ++mi)
#pragma unroll
    for (int ni = 0; ni < 4; ++ni)
#pragma unroll
      for (int r = 0; r < 4; ++r) {
        int rr = m0 + wm * 64 + mi * 16 + g * 4 + r;
        int cc = n0 + wn * 64 + ni * 16 + li;
        OF[(size_t)rr * 1024 + cc] = acc[mi][ni][r];
      }
}

// ---------------- causal flash attention (swapped-operand, in-register softmax) ----
__global__ __launch_bounds__(256) void attn_kernel(const u16* __restrict__ Q,
                                                   const u16* __restrict__ K,
                                                   const u16* __restrict__ VtP,
                                                   u16* __restrict__ AO) {
  const int bid = blockIdx.x;
  const int qt = 31 - (bid >> 5);      // LPT: longest blocks dispatched first
  const int bh = bid & 31;
  const int b = bh >> 4, h = bh & 15;
  const int tid = threadIdx.x;
  const int wid = tid >> 6, lane = tid & 63;
  const int g = lane >> 4, li = lane & 15;
  const int q0 = qt * 64;

  __shared__ __align__(16) u16 Ks[2][64 * 64];
  __shared__ __align__(16) u16 Vs[2][64 * 64];   // V^T: [d][slot], keys vperm'd

  const u16* Qh = Q + (size_t)bh * 2048 * 64;
  const u16* Kh = K + (size_t)bh * 2048 * 64;
  const u16* Vh = VtP + (size_t)bh * 64 * 2048;

  const int qrow = q0 + wid * 16 + li;   // this lane's q row
  bf16x8 qf[2];
#pragma unroll
  for (int ks = 0; ks < 2; ++ks)
    qf[ks] = ld16(&Qh[(size_t)qrow * 64 + ks * 32 + g * 8]);

  f32x4 accO[4] = {};                    // accO[mi][r] = O[qrow][mi*16+g*4+r]
  float mrun = -1e30f, lrun = 0.f;

  auto STAGE = [&](int buf, int ktile) {
#pragma unroll
    for (int iss = 0; iss < 2; ++iss) {
      int e = iss * 2048 + wid * 512 + lane * 8;
      int row = e >> 6;
      int c0 = (e & 63) ^ ((row & 7) << 3);
      gload_lds16(&Kh[(size_t)(ktile * 64 + row) * 64 + c0],
                  &Ks[buf][iss * 2048 + wid * 512]);
      gload_lds16(&Vh[(size_t)row * 2048 + ktile * 64 + c0],
                  &Vs[buf][iss * 2048 + wid * 512]);
    }
  };

  STAGE(0, 0);
  int cur = 0;

  for (int kt = 0; kt <= qt; ++kt) {
    __syncthreads();                       // stage(cur) landed; prev reads done
    if (kt < qt) STAGE(cur ^ 1, kt + 1);   // prefetch flies under compute

    // S^T = K Q^T: s[ni][r] = S[key = kt*64 + ni*16 + g*4 + r][q = qrow]
    f32x4 s[4];
#pragma unroll
    for (int ni = 0; ni < 4; ++ni) s[ni] = f32x4{0.f, 0.f, 0.f, 0.f};
#pragma unroll
    for (int ks = 0; ks < 2; ++ks) {
      bf16x8 kf[4];
#pragma unroll
      for (int ni = 0; ni < 4; ++ni)
        kf[ni] = ld16(&Ks[cur][(ni * 16 + li) * 64 + ((ks * 32 + g * 8) ^ ((li & 7) << 3))]);
#pragma unroll
      for (int ni = 0; ni < 4; ++ni) s[ni] = mfma16(kf[ni], qf[ks], s[ni]);
    }

    if (kt == qt) {  // diagonal tile: causal mask (key_local > q_local)
      int ql = wid * 16 + li;
#pragma unroll
      for (int ni = 0; ni < 4; ++ni)
#pragma unroll
        for (int r = 0; r < 4; ++r)
          if (ni * 16 + g * 4 + r > ql) s[ni][r] = -1e30f;
    }

    // in-lane row max over 16 values + 2 shfl across g-groups
    float pmax;
    {
      float m01 = fmaxf(fmaxf(fmaxf(s[0][0], s[0][1]), fmaxf(s[0][2], s[0][3])),
                        fmaxf(fmaxf(s[1][0], s[1][1]), fmaxf(s[1][2], s[1][3])));
      float m23 = fmaxf(fmaxf(fmaxf(s[2][0], s[2][1]), fmaxf(s[2][2], s[2][3])),
                        fmaxf(fmaxf(s[3][0], s[3][1]), fmaxf(s[3][2], s[3][3])));
      pmax = fmaxf(m01, m23);
      pmax = fmaxf(pmax, __shfl_xor(pmax, 16));
      pmax = fmaxf(pmax, __shfl_xor(pmax, 32));
    }

    // defer-max (T13): only rescale when the running max grew by > 8 (log2)
    if (!__all(pmax - mrun <= 8.0f)) {
      float mnew = fmaxf(mrun, pmax);
      float al = exp2f(mrun - mnew);
      mrun = mnew;
      lrun *= al;
#pragma unroll
      for (int mi = 0; mi < 4; ++mi) accO[mi] *= al;
    }

    // exp2 + in-lane sum + 2 shfl
    float rs;
    {
#pragma unroll
      for (int ni = 0; ni < 4; ++ni)
#pragma unroll
        for (int r = 0; r < 4; ++r) s[ni][r] = exp2f(s[ni][r] - mrun);
      float a0 = (s[0][0] + s[0][1]) + (s[0][2] + s[0][3]);
      float a1 = (s[1][0] + s[1][1]) + (s[1][2] + s[1][3]);
      float a2 = (s[2][0] + s[2][1]) + (s[2][2] + s[2][3]);
      float a3 = (s[3][0] + s[3][1]) + (s[3][2] + s[3][3]);
      rs = (a0 + a1) + (a2 + a3);
      rs += __shfl_xor(rs, 16);
      rs += __shfl_xor(rs, 32);
      lrun += rs;
    }

    // pack P into the two PV B-fragments (register-only, matches vperm layout)
    union { u32 u[4]; bf16x8 v; } pf0, pf1;
    pf0.u[0] = pk2(s[0][0], s[0][1]); pf0.u[1] = pk2(s[0][2], s[0][3]);
    pf0.u[2] = pk2(s[1][0], s[1][1]); pf0.u[3] = pk2(s[1][2], s[1][3]);
    pf1.u[0] = pk2(s[2][0], s[2][1]); pf1.u[1] = pk2(s[2][2], s[2][3]);
    pf1.u[2] = pk2(s[3][0], s[3][1]); pf1.u[3] = pk2(s[3][2], s[3][3]);

    // O^T += V^T P : accO[mi] over d = mi*16 + g*4 + r, q = qrow
#pragma unroll
    for (int ks = 0; ks < 2; ++ks) {
      bf16x8 pf = ks ? pf1.v : pf0.v;
#pragma unroll
      for (int mi = 0; mi < 4; ++mi) {
        bf16x8 vf = ld16(&Vs[cur][(mi * 16 + li) * 64 + ((ks * 32 + g * 8) ^ ((li & 7) << 3))]);
        accO[mi] = mfma16(vf, pf, accO[mi]);
      }
    }
    cur ^= 1;
  }

  // epilogue: normalize, transpose through LDS (reuse Ks), coalesced stores
  float inv = __builtin_amdgcn_rcpf(lrun);
  __syncthreads();
  u16* E = (u16*)Ks;                    // [64 q][64 d], XOR-swizzled
  int erow = wid * 16 + li;
#pragma unroll
  for (int mi = 0; mi < 4; ++mi) {
    uint2 wv;
    wv.x = pk2(accO[mi][0] * inv, accO[mi][1] * inv);
    wv.y = pk2(accO[mi][2] * inv, accO[mi][3] * inv);
    *(uint2*)&E[erow * 64 + ((mi * 16 + g * 4) ^ ((li & 7) << 3))] = wv;
  }
  __syncthreads();
#pragma unroll
  for (int pass = 0; pass < 2; ++pass) {
    int idx = pass * 2048 + tid * 8;
    int row = idx >> 6, col = idx & 63;
    uint4 val = *(uint4*)&E[row * 64 + (col ^ ((row & 7) << 3))];
    *(uint4*)&AO[(size_t)(b * 2048 + q0 + row) * 1024 + h * 64 + col] = val;
  }
}

// ---------------- launch ----------------

extern "C" void kernel_launch(void* const* d_in, const int* in_sizes, int n_in,
                              void* d_out, int out_size, void* d_ws, size_t ws_size,
                              hipStream_t stream) {
  const float* X = (const float*)d_in[0];
  const float* Wqkv = (const float*)d_in[1];
  const float* Wproj = (const float*)d_in[2];
  float* out = (float*)d_out;

  u16* ws = (u16*)d_ws;
  u16* Xb = ws;                        // 4194304 (reused as VtP after gemm1)
  u16* Wqkvt = Xb + 4194304;           // 3145728
  u16* Wprojt = Wqkvt + 3145728;       // 1048576
  u16* Qb = Wprojt + 1048576;          // 4194304
  u16* Kb = Qb + 4194304;              // 4194304
  u16* Vb = Kb + 4194304;              // 4194304
  u16* AO = Vb + 4194304;              // 4194304  (total 50,331,648 B)
  u16* VtP = Xb;                       // alias: Xb dead after gemm1

  cvt_x_kernel<<<2048, 256, 0, stream>>>(X, Xb);
  transpose_w_kernel<<<16 * 48, 256, 0, stream>>>(Wqkv, Wqkvt, 1024, 3072);
  transpose_w_kernel<<<16 * 16, 256, 0, stream>>>(Wproj, Wprojt, 1024, 1024);
  gemm256_qkv_kernel<<<192, 512, 0, stream>>>(Xb, Wqkvt, Qb, Kb, Vb);
  transpose_v_kernel<<<1024, 256, 0, stream>>>(Vb, VtP);
  attn_kernel<<<1024, 256, 0, stream>>>(Qb, Kb, VtP, AO);
  gemm_proj_kernel<<<32 * 8, 256, 0, stream>>>(AO, Wprojt, out);
}